// Round 14
// baseline (193.159 us; speedup 1.0000x reference)
//
#include <hip/hip_runtime.h>
#include <stdint.h>

#define AS1 __attribute__((address_space(1)))
#define AS3 __attribute__((address_space(3)))

typedef __attribute__((ext_vector_type(8))) short bf16x8;    // 8 x bf16 (4 VGPRs)
typedef __attribute__((ext_vector_type(4))) float f32x4;     // MFMA 16x16 C/D
typedef __attribute__((ext_vector_type(16))) float f32x16;   // MFMA 32x32 C/D

// R17 (verified): hardware f32->bf16 RNE cvt — 1 inst vs 4 VALU. RNE==RNE.
__device__ __forceinline__ unsigned short f32_bf16(float f) {
  __bf16 b = (__bf16)f;                     // fptrunc -> native RNE cvt on gfx950
  union { __bf16 b; unsigned short u; } cv;
  cv.b = b;
  return cv.u;
}

__device__ __forceinline__ void async_ld16(const unsigned short* g, unsigned short* l) {
  // global -> LDS direct, 16B per lane; LDS dest must be base + lane*16 contiguous
  __builtin_amdgcn_global_load_lds((const AS1 void*)g, (AS3 void*)l, 16, 0, 0);
}

// ---------------- fused prep: cvt x + transpose w_qkv + transpose w_out + RoPE table ----
__device__ __forceinline__ void transpose_tile(const float* __restrict__ src,
                                               unsigned short* __restrict__ dst,
                                               int K, int N, int nt, int kt,
                                               unsigned short (*tile)[65]) {
  int t = threadIdx.x;
  #pragma unroll
  for (int i = 0; i < 16; ++i) {
    int idx = t + i * 256;
    int r = idx >> 6, c = idx & 63;
    tile[r][c] = f32_bf16(src[(size_t)(kt * 64 + r) * N + nt * 64 + c]);
  }
  __syncthreads();
  #pragma unroll
  for (int i = 0; i < 16; ++i) {
    int idx = t + i * 256;
    int r = idx >> 6, c = idx & 63;
    dst[(size_t)(nt * 64 + r) * K + kt * 64 + c] = tile[c][r];
  }
}

__global__ __launch_bounds__(256) void prep(const float* __restrict__ x,
                                            const float* __restrict__ w_qkv,
                                            const float* __restrict__ w_out,
                                            unsigned short* __restrict__ Xb,
                                            unsigned short* __restrict__ WqkvT,
                                            unsigned short* __restrict__ WoT,
                                            float2* __restrict__ ropeT) {
  __shared__ unsigned short tile[64][65];
  int bid = blockIdx.x;
  if (bid < 4096) {
    // cvt: 4096 blocks x 256 threads x float4 = exactly 2*2048*1024 floats
    int i = bid * 256 + threadIdx.x;
    float4 v = ((const float4*)x)[i];
    ushort4 o;
    o.x = f32_bf16(v.x); o.y = f32_bf16(v.y); o.z = f32_bf16(v.z); o.w = f32_bf16(v.w);
    ((ushort4*)Xb)[i] = o;
  } else if (bid < 4864) {
    int b2 = bid - 4096;                 // w_qkv [1024][3072] -> [3072][1024]
    transpose_tile(w_qkv, WqkvT, 1024, 3072, b2 % 48, b2 / 48, tile);
  } else if (bid < 5120) {
    int b2 = bid - 4864;                 // w_out [1024][1024] -> [1024][1024]^T
    transpose_tile(w_out, WoT, 1024, 1024, b2 % 16, b2 / 16, tile);
  } else {
    // RoPE table: ropeT[s][p] = (cos(s*f_p), sin(s*f_p)), f_p = 1e4^(-p/32)
    int idx = (bid - 5120) * 256 + threadIdx.x;   // 256 blocks -> 65536 = 2048*32
    int s = idx >> 5, p = idx & 31;
    float invf = exp2f((float)p * (-13.287712379549449f / 32.f));
    float sn, cs;
    __sincosf((float)s * invf, &sn, &cs);
    ropeT[idx] = make_float2(cs, sn);
  }
}

// ------------- 128x128 bf16 MFMA GEMM core, BK=64 (R20, verified) -------------
template <int KDIM>
__device__ __forceinline__ void gemm_core_k64(const unsigned short* __restrict__ A,
                                              const unsigned short* __restrict__ Bt,
                                              unsigned short* Als, unsigned short* Bls,
                                              int bm, int bn, f32x4 (&acc)[4][4]) {
  const int tid = threadIdx.x;
  const int w = tid >> 6, lane = tid & 63, quad = lane >> 4, l15 = lane & 15;
  const int wr = w >> 1, wc = w & 1;
  const int srow = lane >> 2, scol = (lane & 3) * 8;
  const unsigned short* Arow0 = A + (size_t)(bm * 128) * KDIM;
  const unsigned short* Brow0 = Bt + (size_t)(bn * 128) * KDIM;
  for (int k0 = 0; k0 < KDIM; k0 += 64) {
    __syncthreads();
    #pragma unroll
    for (int i = 0; i < 4; ++i) {
      int row = (i & 1) * 64 + w * 16 + srow;
      int kadd = (i >> 1) * 32 + scol;
      async_ld16(Arow0 + (size_t)row * KDIM + k0 + kadd, Als + i * 2048 + w * 512 + lane * 8);
      async_ld16(Brow0 + (size_t)row * KDIM + k0 + kadd, Bls + i * 2048 + w * 512 + lane * 8);
    }
    __syncthreads();   // one drain per 64 K
    #pragma unroll
    for (int kk2 = 0; kk2 < 2; ++kk2) {
      bf16x8 a[4], b[4];
      #pragma unroll
      for (int mi = 0; mi < 4; ++mi)
        a[mi] = *(const bf16x8*)(Als + kk2 * 4096 + (wr * 64 + mi * 16 + l15) * 32 + quad * 8);
      #pragma unroll
      for (int ni = 0; ni < 4; ++ni)
        b[ni] = *(const bf16x8*)(Bls + kk2 * 4096 + (wc * 64 + ni * 16 + l15) * 32 + quad * 8);
      #pragma unroll
      for (int mi = 0; mi < 4; ++mi)
        #pragma unroll
        for (int ni = 0; ni < 4; ++ni)
          acc[mi][ni] = __builtin_amdgcn_mfma_f32_16x16x32_bf16(a[mi], b[ni], acc[mi][ni], 0, 0, 0);
    }
  }
}

// ------------- QKV GEMM + bias + RoPE epilogue (coalesced via per-wave LDS) -------------
// R19 (verified): 36,864B aliased pool -> 4 blocks/CU. R20 (verified): BK=64.
__global__ __launch_bounds__(256, 4) void qkv_gemm(const unsigned short* __restrict__ Xb,
                                                   const unsigned short* __restrict__ WqkvT,
                                                   const float* __restrict__ qbias,
                                                   const float* __restrict__ vbias,
                                                   const float2* __restrict__ ropeT,
                                                   unsigned short* __restrict__ Qg,
                                                   unsigned short* __restrict__ Kg,
                                                   unsigned short* __restrict__ Vtg) {
  __shared__ unsigned short shm[4 * 64 * 72];   // 36,864B pool (staging ∪ epilogue)
  unsigned short* Als = shm;                    // 2 sub x [128][32] = 16,384B
  unsigned short* Bls = shm + 8192;             // 2 sub x [128][32] = 16,384B
  f32x4 acc[4][4] = {};
  const int bn = blockIdx.x, bm = blockIdx.y;
  gemm_core_k64<1024>(Xb, WqkvT, Als, Bls, bm, bn, acc);
  __syncthreads();   // all waves done reading Als/Bls before the pool is rewritten

  const int tid = threadIdx.x;
  const int w = tid >> 6, lane = tid & 63, quad = lane >> 4, l15 = lane & 15;
  const int wr = w >> 1, wc = w & 1;
  const int part = bn >> 3;            // 0=q, 1=k, 2=v  (8 n-blocks per part)
  const int cb = (bn & 7) * 128 + wc * 64;     // wave channel base (one full head)
  const int h = cb >> 6;
  const int m0 = bm * 128 + wr * 64;           // wave row base (64 consecutive s)
  const int bb = m0 >> 11, s0 = m0 & 2047;
  unsigned short* Sw = shm + w * 4608;          // per-wave 9,216B epilogue buffer

  if (part < 2) {
    // ---- Q/K: bias + RoPE (table). Q pre-scaled by (1/8)*log2(e). ----
    const float qscale = (part == 0) ? 0.18033688011112042f : 1.f;  // 0.125*log2(e)
    #pragma unroll
    for (int ni = 0; ni < 4; ++ni) {
      int dd = ni * 16 + l15;                  // 0..63 within head
      float bias = (part == 0) ? qbias[cb + dd] : 0.f;
      float sgn = (dd & 1) ? 1.f : -1.f;
      const float2* tp = ropeT + (size_t)s0 * 32 + (dd >> 1);
      #pragma unroll
      for (int mi = 0; mi < 4; ++mi) {
        #pragma unroll
        for (int r = 0; r < 4; ++r) {
          int sl = mi * 16 + quad * 4 + r;     // s_local 0..63
          float val = acc[mi][ni][r] + bias;
          float partner = __shfl_xor(val, 1);  // rotary pair lives in lane^1
          float2 cssn = tp[sl * 32];           // (cos, sin) for (s0+sl, dd>>1)
          val = (val * cssn.x + sgn * partner * cssn.y) * qscale;
          Sw[sl * 72 + dd] = f32_bf16(val);
        }
      }
    }
    unsigned short* dstp = (part == 0) ? Qg : Kg;
    const size_t base = ((size_t)(bb * 16 + h) * 2048 + s0) * 64;  // contiguous 8KB region
    #pragma unroll
    for (int it = 0; it < 8; ++it) {
      int row = it * 8 + (lane >> 3), off = (lane & 7) * 8;
      bf16x8 v = *(const bf16x8*)(Sw + row * 72 + off);
      *(bf16x8*)(dstp + base + (size_t)row * 64 + off) = v;
    }
  } else {
    // ---- V: bias, stage tile [s][d] pad 68, write V^T rows (128B contiguous each) ----
    #pragma unroll
    for (int ni = 0; ni < 4; ++ni) {
      int dd = ni * 16 + l15;
      float bias = vbias[cb + dd];
      #pragma unroll
      for (int mi = 0; mi < 4; ++mi)
        #pragma unroll
        for (int r = 0; r < 4; ++r) {
          int sl = mi * 16 + quad * 4 + r;
          Sw[sl * 68 + dd] = f32_bf16(acc[mi][ni][r] + bias);
        }
    }
    const size_t vbase = (size_t)(bb * 16 + h) * 64 * 2048 + s0;
    #pragma unroll 4
    for (int dd = 0; dd < 64; ++dd) {
      unsigned short v = Sw[lane * 68 + dd];   // column read (tile transpose)
      Vtg[vbase + (size_t)dd * 2048 + lane] = v;  // 64 lanes x 2B = 128B contiguous
    }
  }
}

// ------------- causal flash attention (R23: 32x32 MFMA, 32 q-rows/wave) -------------
// R22 post-mortem: occupancy did NOT move with the LDS shave -> not LDS-capped.
// Floor analysis: 18 ds_read_b128 x 12cy per 64-key tile-wave x 4 waves x 66
// tiles/CU ~ 24us of LDS-read occupancy = 56% of the 42.9us kernel. Each wave
// re-read full K/V for only 16 q-rows. R23: 32x32x16 MFMA, 32 q-rows/wave,
// 128-row blocks (grid 512): same K/V tile serves 2x q-rows -> LDS reads/q-row
// 1.125 -> 0.625 b128 (-44%), block-tiles 16.9k -> 8.7k, barriers halved.
// C/D layout (verified m74/m101): col=lane&31, row=(reg&3)+8(reg>>2)+4(lane>>5);
// A: row=lane&31, k=(lane>>5)*8+e; B: col=lane&31, k=(lane>>5)*8+e (16x16 analog).
// Balance: CU pair {s,s+8} -> qt+qt'=15 -> 34 iters/CU uniform; same bh on both.
// LDS 16+16+8 = 40,960 -> 2 blocks/CU (grid provides exactly 2). (256,2): no cap.
__global__ __launch_bounds__(256, 2) void attn_fwd(const unsigned short* __restrict__ Qg,
                                                   const unsigned short* __restrict__ Kg,
                                                   const unsigned short* __restrict__ Vtg,
                                                   unsigned short* __restrict__ Og) {
  __shared__ unsigned short Kls[2][2 * 64 * 32];  // 16KB dbuf x [d-sub][key 0..63][32 d]
  __shared__ unsigned short Vls[2][2 * 64 * 32];  // 16KB dbuf x [key-chunk][d 0..63][32 key]
  __shared__ unsigned short Pls[4][32 * 32];      //  8KB per-wave P [q-row 0..31][key 0..31]
  const int bid = blockIdx.x;
  const int ix = bid >> 3;                        // 0..63 within this XCD's chunk
  const int bh = ((bid & 7) << 2) + (ix & 3);     // 4 bh per XCD
  const int s = ix >> 2;                          // 0..15
  const int qt = (s < 8) ? s : 23 - s;            // CU pair {s,s+8}: qt+qt'=15
  const int h = bh & 15, b = bh >> 4;
  const int tid = threadIdx.x;
  const int w = tid >> 6, lane = tid & 63;
  const int r32 = lane & 31, hi = lane >> 5;
  const unsigned short* Qb = Qg + (size_t)bh * 2048 * 64;
  const unsigned short* Kb = Kg + (size_t)bh * 2048 * 64;
  const unsigned short* Vb = Vtg + (size_t)bh * 64 * 2048;
  const int q0 = qt * 128 + w * 32;   // 32 q-rows per wave

  // Q fragments (pre-scaled by 0.125*log2e): A-frag kk covers d = kk*16 + hi*8 + 0..7
  bf16x8 aq[4];
  #pragma unroll
  for (int kk = 0; kk < 4; ++kk)
    aq[kk] = *(const bf16x8*)(Qb + (size_t)(q0 + r32) * 64 + kk * 16 + hi * 8);

  f32x16 o0 = {}, o1 = {};             // O accumulators, d-halves (static names: rule #20)
  float l_st[16];
  #pragma unroll
  for (int r = 0; r < 16; ++r) l_st[r] = 0.f;

  unsigned short* Pw = Pls[w];
  const int nkt = 2 * qt + 2;          // 64-key tiles covering keys <= qt*128+127

  const int srow = tid >> 2, scol = (tid & 3) * 8;

  // prologue: stage tile 0 into buffer 0 (same linear gload_lds map as R21/R22)
  #pragma unroll
  for (int i = 0; i < 2; ++i) {
    async_ld16(Kb + (size_t)srow * 64 + i * 32 + scol, Kls[0] + i * 2048 + tid * 8);
    async_ld16(Vb + (size_t)srow * 2048 + i * 32 + scol, Vls[0] + i * 2048 + tid * 8);
  }

  for (int kt = 0; kt < nkt; ++kt) {
    __syncthreads();   // drains vmcnt: buf[kt&1] ready; other buffer free to restage
    const int cur = kt & 1;
    if (kt + 1 < nkt) {                // block-uniform branch
      const int nxt = cur ^ 1;
      #pragma unroll
      for (int i = 0; i < 2; ++i) {
        async_ld16(Kb + (size_t)((kt + 1) * 64 + srow) * 64 + i * 32 + scol,
                   Kls[nxt] + i * 2048 + tid * 8);
        async_ld16(Vb + (size_t)srow * 2048 + (kt + 1) * 64 + i * 32 + scol,
                   Vls[nxt] + i * 2048 + tid * 8);
      }
    }
    const unsigned short* Kbuf = Kls[cur];
    const unsigned short* Vbuf = Vls[cur];

    // two 32-key chunks per tile
    #pragma unroll
    for (int kc = 0; kc < 2; ++kc) {
      // S chunk = Q K^T (32q x 32keys), exp2 domain
      f32x16 sc = {};
      #pragma unroll
      for (int kk = 0; kk < 4; ++kk) {
        bf16x8 bk = *(const bf16x8*)(Kbuf + (kk >> 1) * 2048 + (kc * 32 + r32) * 32 +
                                     (kk & 1) * 16 + hi * 8);
        sc = __builtin_amdgcn_mfma_f32_32x32x16_bf16(aq[kk], bk, sc, 0, 0, 0);
      }

      // p = 2^(s-8); masked -> 0 only possible in the last two tiles (kt >= 2qt).
      if (kt >= 2 * qt) {
        int key = kt * 64 + kc * 32 + r32;
        #pragma unroll
        for (int r = 0; r < 16; ++r) {
          int rowl = (r & 3) + 8 * (r >> 2) + 4 * hi;
          float pv = __builtin_amdgcn_exp2f(sc[r] - 8.f);
          pv = (key > q0 + rowl) ? 0.f : pv;
          l_st[r] += pv;
          Pw[rowl * 32 + r32] = f32_bf16(pv);
        }
      } else {
        #pragma unroll
        for (int r = 0; r < 16; ++r) {
          int rowl = (r & 3) + 8 * (r >> 2) + 4 * hi;
          float pv = __builtin_amdgcn_exp2f(sc[r] - 8.f);
          l_st[r] += pv;
          Pw[rowl * 32 + r32] = f32_bf16(pv);
        }
      }

      // O += P V (A=P rows, 16 keys per step; B=V^T rows). Same-wave ds ordering
      // makes write->read->write on the shared Pw safe without barriers (R22-proven).
      #pragma unroll
      for (int ks = 0; ks < 2; ++ks) {
        bf16x8 ap  = *(const bf16x8*)(Pw + r32 * 32 + ks * 16 + hi * 8);
        bf16x8 bv0 = *(const bf16x8*)(Vbuf + kc * 2048 + (r32) * 32 + ks * 16 + hi * 8);
        bf16x8 bv1 = *(const bf16x8*)(Vbuf + kc * 2048 + (32 + r32) * 32 + ks * 16 + hi * 8);
        o0 = __builtin_amdgcn_mfma_f32_32x32x16_bf16(ap, bv0, o0, 0, 0, 0);
        o1 = __builtin_amdgcn_mfma_f32_32x32x16_bf16(ap, bv1, o1, 0, 0, 0);
      }
    }
  }

  // epilogue: reduce l across the 32 col-lanes of each row, normalize, store.
  #pragma unroll
  for (int r = 0; r < 16; ++r) {
    float s2 = l_st[r];
    s2 += __shfl_xor(s2, 1);
    s2 += __shfl_xor(s2, 2);
    s2 += __shfl_xor(s2, 4);
    s2 += __shfl_xor(s2, 8);
    s2 += __shfl_xor(s2, 16);          // lane^16 stays within the hi group
    l_st[r] = 1.f / s2;
  }
  const size_t ob = ((size_t)b * 2048) * 1024 + (size_t)h * 64;
  #pragma unroll
  for (int r = 0; r < 16; ++r) {
    int row = q0 + (r & 3) + 8 * (r >> 2) + 4 * hi;
    size_t base = ob + (size_t)row * 1024;
    Og[base + r32]      = f32_bf16(o0[r] * l_st[r]);   // 32 lanes x 2B = 64B contiguous
    Og[base + 32 + r32] = f32_bf16(o1[r] * l_st[r]);
  }
}

// ------------- output projection (R16 64x128 tiles + R20 BK=64, verified) -----------
__global__ __launch_bounds__(256, 4) void out_gemm(const unsigned short* __restrict__ Og,
                                                   const unsigned short* __restrict__ WoT,
                                                   float* __restrict__ Cout) {
  __shared__ unsigned short Als[2 * 64 * 32];    //  8KB
  __shared__ unsigned short Bls[2 * 128 * 32];   // 16KB
  f32x4 acc[4][2] = {};
  const int bn = blockIdx.x, bm = blockIdx.y;
  const int tid = threadIdx.x;
  const int w = tid >> 6, lane = tid & 63, quad = lane >> 4, l15 = lane & 15;
  const int srow = lane >> 2, scol = (lane & 3) * 8;
  const unsigned short* Arow0 = Og + (size_t)(bm * 64) * 1024;
  const unsigned short* Brow0 = WoT + (size_t)(bn * 128) * 1024;
  for (int k0 = 0; k0 < 1024; k0 += 64) {
    __syncthreads();
    #pragma unroll
    for (int i = 0; i < 2; ++i) {
      int arow = w * 16 + srow;
      async_ld16(Arow0 + (size_t)arow * 1024 + k0 + i * 32 + scol,
                 Als + i * 2048 + w * 512 + lane * 8);
    }
    #pragma unroll
    for (int i = 0; i < 4; ++i) {
      int brow = (i & 1) * 64 + w * 16 + srow;
      int kadd = (i >> 1) * 32 + scol;
      async_ld16(Brow0 + (size_t)brow * 1024 + k0 + kadd,
                 Bls + i * 2048 + w * 512 + lane * 8);
    }
    __syncthreads();
    #pragma unroll
    for (int kk2 = 0; kk2 < 2; ++kk2) {
      bf16x8 a[4], b[2];
      #pragma unroll
      for (int mi = 0; mi < 4; ++mi)
        a[mi] = *(const bf16x8*)(Als + kk2 * 2048 + (mi * 16 + l15) * 32 + quad * 8);
      #pragma unroll
      for (int ni = 0; ni < 2; ++ni)
        b[ni] = *(const bf16x8*)(Bls + kk2 * 4096 + (w * 32 + ni * 16 + l15) * 32 + quad * 8);
      #pragma unroll
      for (int mi = 0; mi < 4; ++mi)
        #pragma unroll
        for (int ni = 0; ni < 2; ++ni)
          acc[mi][ni] = __builtin_amdgcn_mfma_f32_16x16x32_bf16(a[mi], b[ni], acc[mi][ni], 0, 0, 0);
    }
  }
  #pragma unroll
  for (int mi = 0; mi < 4; ++mi)
    #pragma unroll
    for (int r = 0; r < 4; ++r) {
      int mm = bm * 64 + mi * 16 + quad * 4 + r;
      #pragma unroll
      for (int ni = 0; ni < 2; ++ni) {
        int n = bn * 128 + w * 32 + ni * 16 + l15;
        Cout[(size_t)mm * 1024 + n] = acc[mi][ni][r];  // 64B full line per quad
      }
    }
}

extern "C" void kernel_launch(void* const* d_in, const int* in_sizes, int n_in,
                              void* d_out, int out_size, void* d_ws, size_t ws_size,
                              hipStream_t stream) {
  const float* x      = (const float*)d_in[0];
  const float* w_qkv  = (const float*)d_in[1];
  const float* q_bias = (const float*)d_in[2];
  const float* v_bias = (const float*)d_in[3];
  const float* w_out  = (const float*)d_in[4];
  float* out = (float*)d_out;

  char* ws = (char*)d_ws;                       // 48.5 MB used
  unsigned short* Xb    = (unsigned short*)(ws);                  //  8 MB  x bf16 [4096][1024]
  unsigned short* WqkvT = (unsigned short*)(ws + (8u  << 20));    //  6 MB  w_qkv^T bf16 [3072][1024]
  unsigned short* WoT   = (unsigned short*)(ws + (14u << 20));    //  2 MB  w_out^T bf16 [1024][1024]
  unsigned short* Qg    = (unsigned short*)(ws + (16u << 20));    //  8 MB  Q [B,H,S,D] (x 0.125*log2e)
  unsigned short* Kg    = (unsigned short*)(ws + (24u << 20));    //  8 MB  K [B,H,S,D]
  unsigned short* Vtg   = (unsigned short*)(ws + (32u << 20));    //  8 MB  V^T [B,H,D,S]
  unsigned short* Og    = (unsigned short*)(ws + (40u << 20));    //  8 MB  attn out [B,S,C]
  float2* ropeT         = (float2*)(ws + (48u << 20));            // 512 KB [2048][32] (cos,sin)

  prep<<<5376, 256, 0, stream>>>(x, w_qkv, w_out, Xb, WqkvT, WoT, ropeT);
  qkv_gemm<<<dim3(24, 32), 256, 0, stream>>>(Xb, WqkvT, q_bias, v_bias, ropeT, Qg, Kg, Vtg);
  attn_fwd<<<512, 256, 0, stream>>>(Qg, Kg, Vtg, Og);
  out_gemm<<<dim3(8, 64), 256, 0, stream>>>(Og, WoT, out);
}

// Round 15
// 174.514 us; speedup vs baseline: 1.1068x; 1.1068x over previous
//
#include <hip/hip_runtime.h>
#include <stdint.h>

#define AS1 __attribute__((address_space(1)))
#define AS3 __attribute__((address_space(3)))

typedef __attribute__((ext_vector_type(8))) short bf16x8;  // 8 x bf16 (4 VGPRs)
typedef __attribute__((ext_vector_type(4))) float f32x4;   // MFMA 16x16 C/D

// R17 (verified): hardware f32->bf16 RNE cvt — 1 inst vs 4 VALU. RNE==RNE.
__device__ __forceinline__ unsigned short f32_bf16(float f) {
  __bf16 b = (__bf16)f;                     // fptrunc -> native RNE cvt on gfx950
  union { __bf16 b; unsigned short u; } cv;
  cv.b = b;
  return cv.u;
}

__device__ __forceinline__ void async_ld16(const unsigned short* g, unsigned short* l) {
  // global -> LDS direct, 16B per lane; LDS dest must be base + lane*16 contiguous
  __builtin_amdgcn_global_load_lds((const AS1 void*)g, (AS3 void*)l, 16, 0, 0);
}

// ---------------- fused prep: cvt x + transpose w_qkv + transpose w_out + RoPE table ----
__device__ __forceinline__ void transpose_tile(const float* __restrict__ src,
                                               unsigned short* __restrict__ dst,
                                               int K, int N, int nt, int kt,
                                               unsigned short (*tile)[65]) {
  int t = threadIdx.x;
  #pragma unroll
  for (int i = 0; i < 16; ++i) {
    int idx = t + i * 256;
    int r = idx >> 6, c = idx & 63;
    tile[r][c] = f32_bf16(src[(size_t)(kt * 64 + r) * N + nt * 64 + c]);
  }
  __syncthreads();
  #pragma unroll
  for (int i = 0; i < 16; ++i) {
    int idx = t + i * 256;
    int r = idx >> 6, c = idx & 63;
    dst[(size_t)(nt * 64 + r) * K + kt * 64 + c] = tile[c][r];
  }
}

__global__ __launch_bounds__(256) void prep(const float* __restrict__ x,
                                            const float* __restrict__ w_qkv,
                                            const float* __restrict__ w_out,
                                            unsigned short* __restrict__ Xb,
                                            unsigned short* __restrict__ WqkvT,
                                            unsigned short* __restrict__ WoT,
                                            float2* __restrict__ ropeT) {
  __shared__ unsigned short tile[64][65];
  int bid = blockIdx.x;
  if (bid < 4096) {
    // cvt: 4096 blocks x 256 threads x float4 = exactly 2*2048*1024 floats
    int i = bid * 256 + threadIdx.x;
    float4 v = ((const float4*)x)[i];
    ushort4 o;
    o.x = f32_bf16(v.x); o.y = f32_bf16(v.y); o.z = f32_bf16(v.z); o.w = f32_bf16(v.w);
    ((ushort4*)Xb)[i] = o;
  } else if (bid < 4864) {
    int b2 = bid - 4096;                 // w_qkv [1024][3072] -> [3072][1024]
    transpose_tile(w_qkv, WqkvT, 1024, 3072, b2 % 48, b2 / 48, tile);
  } else if (bid < 5120) {
    int b2 = bid - 4864;                 // w_out [1024][1024] -> [1024][1024]^T
    transpose_tile(w_out, WoT, 1024, 1024, b2 % 16, b2 / 16, tile);
  } else {
    // RoPE table: ropeT[s][p] = (cos(s*f_p), sin(s*f_p)), f_p = 1e4^(-p/32)
    int idx = (bid - 5120) * 256 + threadIdx.x;   // 256 blocks -> 65536 = 2048*32
    int s = idx >> 5, p = idx & 31;
    float invf = exp2f((float)p * (-13.287712379549449f / 32.f));
    float sn, cs;
    __sincosf((float)s * invf, &sn, &cs);
    ropeT[idx] = make_float2(cs, sn);
  }
}

// ------------- 128x128 bf16 MFMA GEMM core, BK=64 (R20, verified) -------------
template <int KDIM>
__device__ __forceinline__ void gemm_core_k64(const unsigned short* __restrict__ A,
                                              const unsigned short* __restrict__ Bt,
                                              unsigned short* Als, unsigned short* Bls,
                                              int bm, int bn, f32x4 (&acc)[4][4]) {
  const int tid = threadIdx.x;
  const int w = tid >> 6, lane = tid & 63, quad = lane >> 4, l15 = lane & 15;
  const int wr = w >> 1, wc = w & 1;
  const int srow = lane >> 2, scol = (lane & 3) * 8;
  const unsigned short* Arow0 = A + (size_t)(bm * 128) * KDIM;
  const unsigned short* Brow0 = Bt + (size_t)(bn * 128) * KDIM;
  for (int k0 = 0; k0 < KDIM; k0 += 64) {
    __syncthreads();
    #pragma unroll
    for (int i = 0; i < 4; ++i) {
      int row = (i & 1) * 64 + w * 16 + srow;
      int kadd = (i >> 1) * 32 + scol;
      async_ld16(Arow0 + (size_t)row * KDIM + k0 + kadd, Als + i * 2048 + w * 512 + lane * 8);
      async_ld16(Brow0 + (size_t)row * KDIM + k0 + kadd, Bls + i * 2048 + w * 512 + lane * 8);
    }
    __syncthreads();   // one drain per 64 K
    #pragma unroll
    for (int kk2 = 0; kk2 < 2; ++kk2) {
      bf16x8 a[4], b[4];
      #pragma unroll
      for (int mi = 0; mi < 4; ++mi)
        a[mi] = *(const bf16x8*)(Als + kk2 * 4096 + (wr * 64 + mi * 16 + l15) * 32 + quad * 8);
      #pragma unroll
      for (int ni = 0; ni < 4; ++ni)
        b[ni] = *(const bf16x8*)(Bls + kk2 * 4096 + (wc * 64 + ni * 16 + l15) * 32 + quad * 8);
      #pragma unroll
      for (int mi = 0; mi < 4; ++mi)
        #pragma unroll
        for (int ni = 0; ni < 4; ++ni)
          acc[mi][ni] = __builtin_amdgcn_mfma_f32_16x16x32_bf16(a[mi], b[ni], acc[mi][ni], 0, 0, 0);
    }
  }
}

// ------------- QKV GEMM + bias + RoPE epilogue (coalesced via per-wave LDS) -------------
// R19 (verified): 36,864B aliased pool -> 4 blocks/CU. R20 (verified): BK=64.
__global__ __launch_bounds__(256, 4) void qkv_gemm(const unsigned short* __restrict__ Xb,
                                                   const unsigned short* __restrict__ WqkvT,
                                                   const float* __restrict__ qbias,
                                                   const float* __restrict__ vbias,
                                                   const float2* __restrict__ ropeT,
                                                   unsigned short* __restrict__ Qg,
                                                   unsigned short* __restrict__ Kg,
                                                   unsigned short* __restrict__ Vtg) {
  __shared__ unsigned short shm[4 * 64 * 72];   // 36,864B pool (staging ∪ epilogue)
  unsigned short* Als = shm;                    // 2 sub x [128][32] = 16,384B
  unsigned short* Bls = shm + 8192;             // 2 sub x [128][32] = 16,384B
  f32x4 acc[4][4] = {};
  const int bn = blockIdx.x, bm = blockIdx.y;
  gemm_core_k64<1024>(Xb, WqkvT, Als, Bls, bm, bn, acc);
  __syncthreads();   // all waves done reading Als/Bls before the pool is rewritten

  const int tid = threadIdx.x;
  const int w = tid >> 6, lane = tid & 63, quad = lane >> 4, l15 = lane & 15;
  const int wr = w >> 1, wc = w & 1;
  const int part = bn >> 3;            // 0=q, 1=k, 2=v  (8 n-blocks per part)
  const int cb = (bn & 7) * 128 + wc * 64;     // wave channel base (one full head)
  const int h = cb >> 6;
  const int m0 = bm * 128 + wr * 64;           // wave row base (64 consecutive s)
  const int bb = m0 >> 11, s0 = m0 & 2047;
  unsigned short* Sw = shm + w * 4608;          // per-wave 9,216B epilogue buffer

  if (part < 2) {
    // ---- Q/K: bias + RoPE (table). Q pre-scaled by (1/8)*log2(e). ----
    const float qscale = (part == 0) ? 0.18033688011112042f : 1.f;  // 0.125*log2(e)
    #pragma unroll
    for (int ni = 0; ni < 4; ++ni) {
      int dd = ni * 16 + l15;                  // 0..63 within head
      float bias = (part == 0) ? qbias[cb + dd] : 0.f;
      float sgn = (dd & 1) ? 1.f : -1.f;
      const float2* tp = ropeT + (size_t)s0 * 32 + (dd >> 1);
      #pragma unroll
      for (int mi = 0; mi < 4; ++mi) {
        #pragma unroll
        for (int r = 0; r < 4; ++r) {
          int sl = mi * 16 + quad * 4 + r;     // s_local 0..63
          float val = acc[mi][ni][r] + bias;
          float partner = __shfl_xor(val, 1);  // rotary pair lives in lane^1
          float2 cssn = tp[sl * 32];           // (cos, sin) for (s0+sl, dd>>1)
          val = (val * cssn.x + sgn * partner * cssn.y) * qscale;
          Sw[sl * 72 + dd] = f32_bf16(val);
        }
      }
    }
    unsigned short* dstp = (part == 0) ? Qg : Kg;
    const size_t base = ((size_t)(bb * 16 + h) * 2048 + s0) * 64;  // contiguous 8KB region
    #pragma unroll
    for (int it = 0; it < 8; ++it) {
      int row = it * 8 + (lane >> 3), off = (lane & 7) * 8;
      bf16x8 v = *(const bf16x8*)(Sw + row * 72 + off);
      *(bf16x8*)(dstp + base + (size_t)row * 64 + off) = v;
    }
  } else {
    // ---- V: bias, stage tile [s][d] pad 68, write V^T rows (128B contiguous each) ----
    #pragma unroll
    for (int ni = 0; ni < 4; ++ni) {
      int dd = ni * 16 + l15;
      float bias = vbias[cb + dd];
      #pragma unroll
      for (int mi = 0; mi < 4; ++mi)
        #pragma unroll
        for (int r = 0; r < 4; ++r) {
          int sl = mi * 16 + quad * 4 + r;
          Sw[sl * 68 + dd] = f32_bf16(acc[mi][ni][r] + bias);
        }
    }
    const size_t vbase = (size_t)(bb * 16 + h) * 64 * 2048 + s0;
    #pragma unroll 4
    for (int dd = 0; dd < 64; ++dd) {
      unsigned short v = Sw[lane * 68 + dd];   // column read (tile transpose)
      Vtg[vbase + (size_t)dd * 2048 + lane] = v;  // 64 lanes x 2B = 128B contiguous
    }
  }
}

// ------------- causal flash attention (R24 = verified R22 body + T2 K/V swizzle) -----
// R23 post-mortem: 32x32 restructure collapsed MFMA ILP (4-deep serial S chain,
// MfmaUtil 15->11%) and doubled scalar-P-store rate — reverted to R22 (42.9us).
// R24 single lever: SQ_LDS_BANK_CONFLICT = 7.16M cyc (~28k/CU, up to ~26% of
// kernel). T2-style XOR chunk swizzle on K/V LDS, rule-#21-compliant: LDS dest
// stays gload_lds-linear; the per-lane GLOBAL source chunk is pre-permuted
// (q_src = (tid&3) ^ ((tid>>2)&3)) and reads apply the same involution
// (quad ^ (l15&3)). Pure layout permutation -> bit-identical output.
__global__ __launch_bounds__(256, 4) void attn_fwd(const unsigned short* __restrict__ Qg,
                                                   const unsigned short* __restrict__ Kg,
                                                   const unsigned short* __restrict__ Vtg,
                                                   unsigned short* __restrict__ Og) {
  __shared__ unsigned short Kls[2][64 * 64];     // 16KB  dbuf x [ki][key][32]
  __shared__ unsigned short Vls[2][64 * 64];     // 16KB  dbuf x [k2][d][32]
  __shared__ unsigned short Pls[4][16 * 32];     //  4KB  per-wave [qrow][32key swz]
  const int bid = blockIdx.x;
  const int ix = bid >> 3;                       // 0..127 within this XCD's chunk
  const int bh = ((bid & 7) << 2) + (ix & 3);    // 4 bh per XCD; same-CU group shares bh
  const int s = ix >> 2;                         // 0..31
  const int m = s & 7, t = s >> 3;
  const int qt = (t == 0) ? m : (t == 1) ? (31 - m) : (t == 2) ? (8 + m) : (23 - m);
  const int h = bh & 15, b = bh >> 4;
  const int tid = threadIdx.x;
  const int w = tid >> 6, lane = tid & 63, quad = lane >> 4, l15 = lane & 15;
  const unsigned short* Qb = Qg + (size_t)bh * 2048 * 64;
  const unsigned short* Kb = Kg + (size_t)bh * 2048 * 64;
  const unsigned short* Vb = Vtg + (size_t)bh * 64 * 2048;
  const int q0 = qt * 64 + w * 16;   // 16 q-rows per wave

  bf16x8 aq[2];   // Q fragments (pre-scaled by 0.125*log2e) stay in registers
  #pragma unroll
  for (int ki = 0; ki < 2; ++ki)
    aq[ki] = *(const bf16x8*)(Qb + (size_t)(q0 + l15) * 64 + ki * 32 + quad * 8);

  f32x4 o[4] = {};
  float l_st[4] = {0.f, 0.f, 0.f, 0.f};   // per-lane partial row sums (linear)

  unsigned short* Pw = Pls[w];
  const int nkt = qt + 1;            // 64-key tiles covering keys <= q0_block+63

  // staging: 256 threads x 4 chunks x 16B = 16KB/tile (8KB K + 8KB V), linear LDS.
  // R24: source chunk pre-swizzled q_src = (tid&3) ^ ((tid>>2)&3) (T2, rule #21).
  const int srow = tid >> 2;
  const int scolx = (((tid & 3) ^ ((tid >> 2) & 3)) * 8);
  const int qx = (quad ^ (l15 & 3)) * 8;         // read-side involution

  // prologue: stage tile 0 into buffer 0
  #pragma unroll
  for (int i = 0; i < 2; ++i) {
    async_ld16(Kb + (size_t)srow * 64 + i * 32 + scolx, Kls[0] + i * 2048 + tid * 8);
    async_ld16(Vb + (size_t)srow * 2048 + i * 32 + scolx, Vls[0] + i * 2048 + tid * 8);
  }

  for (int kt = 0; kt < nkt; ++kt) {
    __syncthreads();   // drains vmcnt: buf[kt&1] ready; prev buffer free to restage
    const int cur = kt & 1;
    if (kt + 1 < nkt) {              // block-uniform branch
      const int nxt = cur ^ 1;
      #pragma unroll
      for (int i = 0; i < 2; ++i) {
        async_ld16(Kb + (size_t)((kt + 1) * 64 + srow) * 64 + i * 32 + scolx,
                   Kls[nxt] + i * 2048 + tid * 8);
        async_ld16(Vb + (size_t)srow * 2048 + (kt + 1) * 64 + i * 32 + scolx,
                   Vls[nxt] + i * 2048 + tid * 8);
      }
    }
    const unsigned short* Kbuf = Kls[cur];
    const unsigned short* Vbuf = Vls[cur];

    // S = Q K^T (per wave: 16 q-rows x 64 keys), already in exp2 domain
    f32x4 sc[4] = {};
    #pragma unroll
    for (int ki = 0; ki < 2; ++ki) {
      bf16x8 bk[4];
      #pragma unroll
      for (int ni = 0; ni < 4; ++ni)
        bk[ni] = *(const bf16x8*)(Kbuf + ki * 2048 + (ni * 16 + l15) * 32 + qx);
      #pragma unroll
      for (int ni = 0; ni < 4; ++ni)
        sc[ni] = __builtin_amdgcn_mfma_f32_16x16x32_bf16(aq[ki], bk[ni], sc[ni], 0, 0, 0);
    }

    // p = 2^(s-8); masked -> 0 (diag tile only). No max-reduce, no rescale.
    if (kt == qt) {
      #pragma unroll
      for (int r = 0; r < 4; ++r) {
        int row = q0 + quad * 4 + r;
        #pragma unroll
        for (int ni = 0; ni < 4; ++ni) {
          bool masked = (kt * 64 + ni * 16 + l15) > row;
          float pv = __builtin_amdgcn_exp2f(sc[ni][r] - 8.f);
          pv = masked ? 0.f : pv;
          sc[ni][r] = pv;
          l_st[r] += pv;
        }
      }
    } else {
      #pragma unroll
      for (int r = 0; r < 4; ++r)
        #pragma unroll
        for (int ni = 0; ni < 4; ++ni) {
          float pv = __builtin_amdgcn_exp2f(sc[ni][r] - 8.f);
          sc[ni][r] = pv;
          l_st[r] += pv;
        }
    }

    // O += P V; both 32-key chunks share ONE 1KB/wave P buffer (R22), chunk
    // swizzle ~2-way. Same-wave ds ordering makes write->read->write safe.
    #pragma unroll
    for (int k4 = 0; k4 < 2; ++k4) {
      #pragma unroll
      for (int nlh = 0; nlh < 2; ++nlh) {
        int nl = k4 * 2 + nlh;
        int ck = (nlh << 1) | (l15 >> 3);
        int cs = ck ^ quad;                    // writer row rw=quad*4+r -> rw>>2=quad
        #pragma unroll
        for (int r = 0; r < 4; ++r) {
          int rw = quad * 4 + r;
          Pw[rw * 32 + cs * 8 + (l15 & 7)] = f32_bf16(sc[nl][r]);
        }
      }
      bf16x8 ap, bv[4];
      int csr = quad ^ ((l15 >> 2) & 3);       // reader row = l15, logical chunk = quad
      ap = *(const bf16x8*)(Pw + l15 * 32 + csr * 8);
      #pragma unroll
      for (int di = 0; di < 4; ++di)
        bv[di] = *(const bf16x8*)(Vbuf + k4 * 2048 + (di * 16 + l15) * 32 + qx);
      #pragma unroll
      for (int di = 0; di < 4; ++di)
        o[di] = __builtin_amdgcn_mfma_f32_16x16x32_bf16(ap, bv[di], o[di], 0, 0, 0);
    }
  }

  // epilogue: ONE cross-lane l reduction, normalize, store in two 32-col halves
  #pragma unroll
  for (int r = 0; r < 4; ++r) {
    float s2 = l_st[r];
    s2 += __shfl_xor(s2, 1);
    s2 += __shfl_xor(s2, 2);
    s2 += __shfl_xor(s2, 4);
    s2 += __shfl_xor(s2, 8);
    l_st[r] = 1.f / s2;
  }
  const size_t ob = ((size_t)(b * 2048 + q0)) * 1024 + h * 64;
  #pragma unroll
  for (int dh = 0; dh < 2; ++dh) {
    #pragma unroll
    for (int r = 0; r < 4; ++r) {
      float inv = l_st[r];
      int sl = quad * 4 + r;
      #pragma unroll
      for (int dl = 0; dl < 2; ++dl) {
        int di = dh * 2 + dl;
        int ck = dl * 2 + (l15 >> 3);
        int cs = ck ^ (sl & 3);
        Pw[sl * 32 + cs * 8 + (l15 & 7)] = f32_bf16(o[di][r] * inv);
      }
    }
    int row = lane >> 2;
    int cr = lane & 3;
    int crs = cr ^ (row & 3);
    bf16x8 v = *(const bf16x8*)(Pw + row * 32 + crs * 8);
    *(bf16x8*)(Og + ob + (size_t)row * 1024 + dh * 32 + cr * 8) = v;
  }
}

// ------------- output projection (R16 64x128 tiles + R20 BK=64, verified) -----------
__global__ __launch_bounds__(256, 4) void out_gemm(const unsigned short* __restrict__ Og,
                                                   const unsigned short* __restrict__ WoT,
                                                   float* __restrict__ Cout) {
  __shared__ unsigned short Als[2 * 64 * 32];    //  8KB
  __shared__ unsigned short Bls[2 * 128 * 32];   // 16KB
  f32x4 acc[4][2] = {};
  const int bn = blockIdx.x, bm = blockIdx.y;
  const int tid = threadIdx.x;
  const int w = tid >> 6, lane = tid & 63, quad = lane >> 4, l15 = lane & 15;
  const int srow = lane >> 2, scol = (lane & 3) * 8;
  const unsigned short* Arow0 = Og + (size_t)(bm * 64) * 1024;
  const unsigned short* Brow0 = WoT + (size_t)(bn * 128) * 1024;
  for (int k0 = 0; k0 < 1024; k0 += 64) {
    __syncthreads();
    #pragma unroll
    for (int i = 0; i < 2; ++i) {
      int arow = w * 16 + srow;
      async_ld16(Arow0 + (size_t)arow * 1024 + k0 + i * 32 + scol,
                 Als + i * 2048 + w * 512 + lane * 8);
    }
    #pragma unroll
    for (int i = 0; i < 4; ++i) {
      int brow = (i & 1) * 64 + w * 16 + srow;
      int kadd = (i >> 1) * 32 + scol;
      async_ld16(Brow0 + (size_t)brow * 1024 + k0 + kadd,
                 Bls + i * 2048 + w * 512 + lane * 8);
    }
    __syncthreads();
    #pragma unroll
    for (int kk2 = 0; kk2 < 2; ++kk2) {
      bf16x8 a[4], b[2];
      #pragma unroll
      for (int mi = 0; mi < 4; ++mi)
        a[mi] = *(const bf16x8*)(Als + kk2 * 2048 + (mi * 16 + l15) * 32 + quad * 8);
      #pragma unroll
      for (int ni = 0; ni < 2; ++ni)
        b[ni] = *(const bf16x8*)(Bls + kk2 * 4096 + (w * 32 + ni * 16 + l15) * 32 + quad * 8);
      #pragma unroll
      for (int mi = 0; mi < 4; ++mi)
        #pragma unroll
        for (int ni = 0; ni < 2; ++ni)
          acc[mi][ni] = __builtin_amdgcn_mfma_f32_16x16x32_bf16(a[mi], b[ni], acc[mi][ni], 0, 0, 0);
    }
  }
  #pragma unroll
  for (int mi = 0; mi < 4; ++mi)
    #pragma unroll
    for (int r = 0; r < 4; ++r) {
      int mm = bm * 64 + mi * 16 + quad * 4 + r;
      #pragma unroll
      for (int ni = 0; ni < 2; ++ni) {
        int n = bn * 128 + w * 32 + ni * 16 + l15;
        Cout[(size_t)mm * 1024 + n] = acc[mi][ni][r];  // 64B full line per quad
      }
    }
}

extern "C" void kernel_launch(void* const* d_in, const int* in_sizes, int n_in,
                              void* d_out, int out_size, void* d_ws, size_t ws_size,
                              hipStream_t stream) {
  const float* x      = (const float*)d_in[0];
  const float* w_qkv  = (const float*)d_in[1];
  const float* q_bias = (const float*)d_in[2];
  const float* v_bias = (const float*)d_in[3];
  const float* w_out  = (const float*)d_in[4];
  float* out = (float*)d_out;

  char* ws = (char*)d_ws;                       // 48.5 MB used
  unsigned short* Xb    = (unsigned short*)(ws);                  //  8 MB  x bf16 [4096][1024]
  unsigned short* WqkvT = (unsigned short*)(ws + (8u  << 20));    //  6 MB  w_qkv^T bf16 [3072][1024]
  unsigned short* WoT   = (unsigned short*)(ws + (14u << 20));    //  2 MB  w_out^T bf16 [1024][1024]
  unsigned short* Qg    = (unsigned short*)(ws + (16u << 20));    //  8 MB  Q [B,H,S,D] (x 0.125*log2e)
  unsigned short* Kg    = (unsigned short*)(ws + (24u << 20));    //  8 MB  K [B,H,S,D]
  unsigned short* Vtg   = (unsigned short*)(ws + (32u << 20));    //  8 MB  V^T [B,H,D,S]
  unsigned short* Og    = (unsigned short*)(ws + (40u << 20));    //  8 MB  attn out [B,S,C]
  float2* ropeT         = (float2*)(ws + (48u << 20));            // 512 KB [2048][32] (cos,sin)

  prep<<<5376, 256, 0, stream>>>(x, w_qkv, w_out, Xb, WqkvT, WoT, ropeT);
  qkv_gemm<<<dim3(24, 32), 256, 0, stream>>>(Xb, WqkvT, q_bias, v_bias, ropeT, Qg, Kg, Vtg);
  attn_fwd<<<1024, 256, 0, stream>>>(Qg, Kg, Vtg, Og);
  out_gemm<<<dim3(8, 64), 256, 0, stream>>>(Og, WoT, out);
}

// Round 16
// 173.374 us; speedup vs baseline: 1.1141x; 1.0066x over previous
//
#include <hip/hip_runtime.h>
#include <stdint.h>

#define AS1 __attribute__((address_space(1)))
#define AS3 __attribute__((address_space(3)))

typedef __attribute__((ext_vector_type(8))) short bf16x8;  // 8 x bf16 (4 VGPRs)
typedef __attribute__((ext_vector_type(4))) float f32x4;   // MFMA 16x16 C/D

// R17 (verified): hardware f32->bf16 RNE cvt — 1 inst vs 4 VALU. RNE==RNE.
__device__ __forceinline__ unsigned short f32_bf16(float f) {
  __bf16 b = (__bf16)f;                     // fptrunc -> native RNE cvt on gfx950
  union { __bf16 b; unsigned short u; } cv;
  cv.b = b;
  return cv.u;
}

__device__ __forceinline__ void async_ld16(const unsigned short* g, unsigned short* l) {
  // global -> LDS direct, 16B per lane; LDS dest must be base + lane*16 contiguous
  __builtin_amdgcn_global_load_lds((const AS1 void*)g, (AS3 void*)l, 16, 0, 0);
}

// ---------------- fused prep: cvt x + transpose w_qkv + transpose w_out + RoPE table ----
__device__ __forceinline__ void transpose_tile(const float* __restrict__ src,
                                               unsigned short* __restrict__ dst,
                                               int K, int N, int nt, int kt,
                                               unsigned short (*tile)[65]) {
  int t = threadIdx.x;
  #pragma unroll
  for (int i = 0; i < 16; ++i) {
    int idx = t + i * 256;
    int r = idx >> 6, c = idx & 63;
    tile[r][c] = f32_bf16(src[(size_t)(kt * 64 + r) * N + nt * 64 + c]);
  }
  __syncthreads();
  #pragma unroll
  for (int i = 0; i < 16; ++i) {
    int idx = t + i * 256;
    int r = idx >> 6, c = idx & 63;
    dst[(size_t)(nt * 64 + r) * K + kt * 64 + c] = tile[c][r];
  }
}

__global__ __launch_bounds__(256) void prep(const float* __restrict__ x,
                                            const float* __restrict__ w_qkv,
                                            const float* __restrict__ w_out,
                                            unsigned short* __restrict__ Xb,
                                            unsigned short* __restrict__ WqkvT,
                                            unsigned short* __restrict__ WoT,
                                            float2* __restrict__ ropeT) {
  __shared__ unsigned short tile[64][65];
  int bid = blockIdx.x;
  if (bid < 4096) {
    // cvt: 4096 blocks x 256 threads x float4 = exactly 2*2048*1024 floats
    int i = bid * 256 + threadIdx.x;
    float4 v = ((const float4*)x)[i];
    ushort4 o;
    o.x = f32_bf16(v.x); o.y = f32_bf16(v.y); o.z = f32_bf16(v.z); o.w = f32_bf16(v.w);
    ((ushort4*)Xb)[i] = o;
  } else if (bid < 4864) {
    int b2 = bid - 4096;                 // w_qkv [1024][3072] -> [3072][1024]
    transpose_tile(w_qkv, WqkvT, 1024, 3072, b2 % 48, b2 / 48, tile);
  } else if (bid < 5120) {
    int b2 = bid - 4864;                 // w_out [1024][1024] -> [1024][1024]^T
    transpose_tile(w_out, WoT, 1024, 1024, b2 % 16, b2 / 16, tile);
  } else {
    // RoPE table: ropeT[s][p] = (cos(s*f_p), sin(s*f_p)), f_p = 1e4^(-p/32)
    int idx = (bid - 5120) * 256 + threadIdx.x;   // 256 blocks -> 65536 = 2048*32
    int s = idx >> 5, p = idx & 31;
    float invf = exp2f((float)p * (-13.287712379549449f / 32.f));
    float sn, cs;
    __sincosf((float)s * invf, &sn, &cs);
    ropeT[idx] = make_float2(cs, sn);
  }
}

// ------------- 128x128 bf16 MFMA GEMM core, BK=64 (R20, verified) -------------
template <int KDIM>
__device__ __forceinline__ void gemm_core_k64(const unsigned short* __restrict__ A,
                                              const unsigned short* __restrict__ Bt,
                                              unsigned short* Als, unsigned short* Bls,
                                              int bm, int bn, f32x4 (&acc)[4][4]) {
  const int tid = threadIdx.x;
  const int w = tid >> 6, lane = tid & 63, quad = lane >> 4, l15 = lane & 15;
  const int wr = w >> 1, wc = w & 1;
  const int srow = lane >> 2, scol = (lane & 3) * 8;
  const unsigned short* Arow0 = A + (size_t)(bm * 128) * KDIM;
  const unsigned short* Brow0 = Bt + (size_t)(bn * 128) * KDIM;
  for (int k0 = 0; k0 < KDIM; k0 += 64) {
    __syncthreads();
    #pragma unroll
    for (int i = 0; i < 4; ++i) {
      int row = (i & 1) * 64 + w * 16 + srow;
      int kadd = (i >> 1) * 32 + scol;
      async_ld16(Arow0 + (size_t)row * KDIM + k0 + kadd, Als + i * 2048 + w * 512 + lane * 8);
      async_ld16(Brow0 + (size_t)row * KDIM + k0 + kadd, Bls + i * 2048 + w * 512 + lane * 8);
    }
    __syncthreads();   // one drain per 64 K
    #pragma unroll
    for (int kk2 = 0; kk2 < 2; ++kk2) {
      bf16x8 a[4], b[4];
      #pragma unroll
      for (int mi = 0; mi < 4; ++mi)
        a[mi] = *(const bf16x8*)(Als + kk2 * 4096 + (wr * 64 + mi * 16 + l15) * 32 + quad * 8);
      #pragma unroll
      for (int ni = 0; ni < 4; ++ni)
        b[ni] = *(const bf16x8*)(Bls + kk2 * 4096 + (wc * 64 + ni * 16 + l15) * 32 + quad * 8);
      #pragma unroll
      for (int mi = 0; mi < 4; ++mi)
        #pragma unroll
        for (int ni = 0; ni < 4; ++ni)
          acc[mi][ni] = __builtin_amdgcn_mfma_f32_16x16x32_bf16(a[mi], b[ni], acc[mi][ni], 0, 0, 0);
    }
  }
}

// ------------- QKV GEMM + bias + RoPE epilogue (coalesced via per-wave LDS) -------------
// R19 (verified): 36,864B aliased pool -> 4 blocks/CU. R20 (verified): BK=64.
__global__ __launch_bounds__(256, 4) void qkv_gemm(const unsigned short* __restrict__ Xb,
                                                   const unsigned short* __restrict__ WqkvT,
                                                   const float* __restrict__ qbias,
                                                   const float* __restrict__ vbias,
                                                   const float2* __restrict__ ropeT,
                                                   unsigned short* __restrict__ Qg,
                                                   unsigned short* __restrict__ Kg,
                                                   unsigned short* __restrict__ Vtg) {
  __shared__ unsigned short shm[4 * 64 * 72];   // 36,864B pool (staging ∪ epilogue)
  unsigned short* Als = shm;                    // 2 sub x [128][32] = 16,384B
  unsigned short* Bls = shm + 8192;             // 2 sub x [128][32] = 16,384B
  f32x4 acc[4][4] = {};
  const int bn = blockIdx.x, bm = blockIdx.y;
  gemm_core_k64<1024>(Xb, WqkvT, Als, Bls, bm, bn, acc);
  __syncthreads();   // all waves done reading Als/Bls before the pool is rewritten

  const int tid = threadIdx.x;
  const int w = tid >> 6, lane = tid & 63, quad = lane >> 4, l15 = lane & 15;
  const int wr = w >> 1, wc = w & 1;
  const int part = bn >> 3;            // 0=q, 1=k, 2=v  (8 n-blocks per part)
  const int cb = (bn & 7) * 128 + wc * 64;     // wave channel base (one full head)
  const int h = cb >> 6;
  const int m0 = bm * 128 + wr * 64;           // wave row base (64 consecutive s)
  const int bb = m0 >> 11, s0 = m0 & 2047;
  unsigned short* Sw = shm + w * 4608;          // per-wave 9,216B epilogue buffer

  if (part < 2) {
    // ---- Q/K: bias + RoPE (table). Q pre-scaled by (1/8)*log2(e). ----
    const float qscale = (part == 0) ? 0.18033688011112042f : 1.f;  // 0.125*log2(e)
    #pragma unroll
    for (int ni = 0; ni < 4; ++ni) {
      int dd = ni * 16 + l15;                  // 0..63 within head
      float bias = (part == 0) ? qbias[cb + dd] : 0.f;
      float sgn = (dd & 1) ? 1.f : -1.f;
      const float2* tp = ropeT + (size_t)s0 * 32 + (dd >> 1);
      #pragma unroll
      for (int mi = 0; mi < 4; ++mi) {
        #pragma unroll
        for (int r = 0; r < 4; ++r) {
          int sl = mi * 16 + quad * 4 + r;     // s_local 0..63
          float val = acc[mi][ni][r] + bias;
          float partner = __shfl_xor(val, 1);  // rotary pair lives in lane^1
          float2 cssn = tp[sl * 32];           // (cos, sin) for (s0+sl, dd>>1)
          val = (val * cssn.x + sgn * partner * cssn.y) * qscale;
          Sw[sl * 72 + dd] = f32_bf16(val);
        }
      }
    }
    unsigned short* dstp = (part == 0) ? Qg : Kg;
    const size_t base = ((size_t)(bb * 16 + h) * 2048 + s0) * 64;  // contiguous 8KB region
    #pragma unroll
    for (int it = 0; it < 8; ++it) {
      int row = it * 8 + (lane >> 3), off = (lane & 7) * 8;
      bf16x8 v = *(const bf16x8*)(Sw + row * 72 + off);
      *(bf16x8*)(dstp + base + (size_t)row * 64 + off) = v;
    }
  } else {
    // ---- V: bias, stage tile [s][d] pad 68, write V^T rows (128B contiguous each) ----
    #pragma unroll
    for (int ni = 0; ni < 4; ++ni) {
      int dd = ni * 16 + l15;
      float bias = vbias[cb + dd];
      #pragma unroll
      for (int mi = 0; mi < 4; ++mi)
        #pragma unroll
        for (int r = 0; r < 4; ++r) {
          int sl = mi * 16 + quad * 4 + r;
          Sw[sl * 68 + dd] = f32_bf16(acc[mi][ni][r] + bias);
        }
    }
    const size_t vbase = (size_t)(bb * 16 + h) * 64 * 2048 + s0;
    #pragma unroll 4
    for (int dd = 0; dd < 64; ++dd) {
      unsigned short v = Sw[lane * 68 + dd];   // column read (tile transpose)
      Vtg[vbase + (size_t)dd * 2048 + lane] = v;  // 64 lanes x 2B = 128B contiguous
    }
  }
}

// ------------- causal flash attention (R25 = exact R22 body, verified 42.9us) --------
// R12 (verified): XCD-chunked bh + balanced qt — FETCH 77->12MB.
// R21 (verified): 64-key 2-phase dbuf staging. R22 (verified): 36,864B LDS, 42.9us.
// R24 post-mortem: chunk-XOR swizzle left SQ_LDS_BANK_CONFLICT byte-identical
// (7,159,808) — conflicts are ROW-structural (64B row stride -> banks alternate
// 0/16), not chunk-driven; swizzle cost VALU for nothing. Reverted.
// Makespan analysis: occupancy 26% = 66 tile-iters/CU over makespan 32 (longest
// causal row) = 2.06 avg blocks — any q-partitioned tiling shares this floor;
// beating it needs key-split + cross-block softmax combine (out of risk budget).
__global__ __launch_bounds__(256, 4) void attn_fwd(const unsigned short* __restrict__ Qg,
                                                   const unsigned short* __restrict__ Kg,
                                                   const unsigned short* __restrict__ Vtg,
                                                   unsigned short* __restrict__ Og) {
  __shared__ unsigned short Kls[2][64 * 64];     // 16KB  dbuf x [ki][key][32]
  __shared__ unsigned short Vls[2][64 * 64];     // 16KB  dbuf x [k2][d][32]
  __shared__ unsigned short Pls[4][16 * 32];     //  4KB  per-wave [qrow][32key swz]
  const int bid = blockIdx.x;
  const int ix = bid >> 3;                       // 0..127 within this XCD's chunk
  const int bh = ((bid & 7) << 2) + (ix & 3);    // 4 bh per XCD; same-CU group shares bh
  const int s = ix >> 2;                         // 0..31
  const int m = s & 7, t = s >> 3;
  const int qt = (t == 0) ? m : (t == 1) ? (31 - m) : (t == 2) ? (8 + m) : (23 - m);
  const int h = bh & 15, b = bh >> 4;
  const int tid = threadIdx.x;
  const int w = tid >> 6, lane = tid & 63, quad = lane >> 4, l15 = lane & 15;
  const unsigned short* Qb = Qg + (size_t)bh * 2048 * 64;
  const unsigned short* Kb = Kg + (size_t)bh * 2048 * 64;
  const unsigned short* Vb = Vtg + (size_t)bh * 64 * 2048;
  const int q0 = qt * 64 + w * 16;   // 16 q-rows per wave

  bf16x8 aq[2];   // Q fragments (pre-scaled by 0.125*log2e) stay in registers
  #pragma unroll
  for (int ki = 0; ki < 2; ++ki)
    aq[ki] = *(const bf16x8*)(Qb + (size_t)(q0 + l15) * 64 + ki * 32 + quad * 8);

  f32x4 o[4] = {};
  float l_st[4] = {0.f, 0.f, 0.f, 0.f};   // per-lane partial row sums (linear)

  unsigned short* Pw = Pls[w];
  const int nkt = qt + 1;            // 64-key tiles covering keys <= q0_block+63

  // staging: 256 threads x 4 chunks x 16B = 16KB/tile (8KB K + 8KB V), linear.
  const int srow = tid >> 2, scol = (tid & 3) * 8;

  // prologue: stage tile 0 into buffer 0
  #pragma unroll
  for (int i = 0; i < 2; ++i) {
    async_ld16(Kb + (size_t)srow * 64 + i * 32 + scol, Kls[0] + i * 2048 + tid * 8);
    async_ld16(Vb + (size_t)srow * 2048 + i * 32 + scol, Vls[0] + i * 2048 + tid * 8);
  }

  for (int kt = 0; kt < nkt; ++kt) {
    __syncthreads();   // drains vmcnt: buf[kt&1] ready; prev buffer free to restage
    const int cur = kt & 1;
    if (kt + 1 < nkt) {              // block-uniform branch
      const int nxt = cur ^ 1;
      #pragma unroll
      for (int i = 0; i < 2; ++i) {
        async_ld16(Kb + (size_t)((kt + 1) * 64 + srow) * 64 + i * 32 + scol,
                   Kls[nxt] + i * 2048 + tid * 8);
        async_ld16(Vb + (size_t)srow * 2048 + (kt + 1) * 64 + i * 32 + scol,
                   Vls[nxt] + i * 2048 + tid * 8);
      }
    }
    const unsigned short* Kbuf = Kls[cur];
    const unsigned short* Vbuf = Vls[cur];

    // S = Q K^T (per wave: 16 q-rows x 64 keys), already in exp2 domain
    f32x4 sc[4] = {};
    #pragma unroll
    for (int ki = 0; ki < 2; ++ki) {
      bf16x8 bk[4];
      #pragma unroll
      for (int ni = 0; ni < 4; ++ni)
        bk[ni] = *(const bf16x8*)(Kbuf + ki * 2048 + (ni * 16 + l15) * 32 + quad * 8);
      #pragma unroll
      for (int ni = 0; ni < 4; ++ni)
        sc[ni] = __builtin_amdgcn_mfma_f32_16x16x32_bf16(aq[ki], bk[ni], sc[ni], 0, 0, 0);
    }

    // p = 2^(s-8); masked -> 0 (diag tile only). No max-reduce, no rescale.
    if (kt == qt) {
      #pragma unroll
      for (int r = 0; r < 4; ++r) {
        int row = q0 + quad * 4 + r;
        #pragma unroll
        for (int ni = 0; ni < 4; ++ni) {
          bool masked = (kt * 64 + ni * 16 + l15) > row;
          float pv = __builtin_amdgcn_exp2f(sc[ni][r] - 8.f);
          pv = masked ? 0.f : pv;
          sc[ni][r] = pv;
          l_st[r] += pv;
        }
      }
    } else {
      #pragma unroll
      for (int r = 0; r < 4; ++r)
        #pragma unroll
        for (int ni = 0; ni < 4; ++ni) {
          float pv = __builtin_amdgcn_exp2f(sc[ni][r] - 8.f);
          sc[ni][r] = pv;
          l_st[r] += pv;
        }
    }

    // O += P V; both 32-key chunks share ONE 1KB/wave P buffer (R22), chunk
    // swizzle ~2-way. Same-wave ds ordering makes write->read->write safe.
    #pragma unroll
    for (int k4 = 0; k4 < 2; ++k4) {
      #pragma unroll
      for (int nlh = 0; nlh < 2; ++nlh) {
        int nl = k4 * 2 + nlh;
        int ck = (nlh << 1) | (l15 >> 3);
        int cs = ck ^ quad;                    // writer row rw=quad*4+r -> rw>>2=quad
        #pragma unroll
        for (int r = 0; r < 4; ++r) {
          int rw = quad * 4 + r;
          Pw[rw * 32 + cs * 8 + (l15 & 7)] = f32_bf16(sc[nl][r]);
        }
      }
      bf16x8 ap, bv[4];
      int csr = quad ^ ((l15 >> 2) & 3);       // reader row = l15, logical chunk = quad
      ap = *(const bf16x8*)(Pw + l15 * 32 + csr * 8);
      #pragma unroll
      for (int di = 0; di < 4; ++di)
        bv[di] = *(const bf16x8*)(Vbuf + k4 * 2048 + (di * 16 + l15) * 32 + quad * 8);
      #pragma unroll
      for (int di = 0; di < 4; ++di)
        o[di] = __builtin_amdgcn_mfma_f32_16x16x32_bf16(ap, bv[di], o[di], 0, 0, 0);
    }
  }

  // epilogue: ONE cross-lane l reduction, normalize, store in two 32-col halves
  #pragma unroll
  for (int r = 0; r < 4; ++r) {
    float s2 = l_st[r];
    s2 += __shfl_xor(s2, 1);
    s2 += __shfl_xor(s2, 2);
    s2 += __shfl_xor(s2, 4);
    s2 += __shfl_xor(s2, 8);
    l_st[r] = 1.f / s2;
  }
  const size_t ob = ((size_t)(b * 2048 + q0)) * 1024 + h * 64;
  #pragma unroll
  for (int dh = 0; dh < 2; ++dh) {
    #pragma unroll
    for (int r = 0; r < 4; ++r) {
      float inv = l_st[r];
      int sl = quad * 4 + r;
      #pragma unroll
      for (int dl = 0; dl < 2; ++dl) {
        int di = dh * 2 + dl;
        int ck = dl * 2 + (l15 >> 3);
        int cs = ck ^ (sl & 3);
        Pw[sl * 32 + cs * 8 + (l15 & 7)] = f32_bf16(o[di][r] * inv);
      }
    }
    int row = lane >> 2;
    int cr = lane & 3;
    int crs = cr ^ (row & 3);
    bf16x8 v = *(const bf16x8*)(Pw + row * 32 + crs * 8);
    *(bf16x8*)(Og + ob + (size_t)row * 1024 + dh * 32 + cr * 8) = v;
  }
}

// ------------- output projection (R16 64x128 tiles + R20 BK=64, verified) -----------
__global__ __launch_bounds__(256, 4) void out_gemm(const unsigned short* __restrict__ Og,
                                                   const unsigned short* __restrict__ WoT,
                                                   float* __restrict__ Cout) {
  __shared__ unsigned short Als[2 * 64 * 32];    //  8KB
  __shared__ unsigned short Bls[2 * 128 * 32];   // 16KB
  f32x4 acc[4][2] = {};
  const int bn = blockIdx.x, bm = blockIdx.y;
  const int tid = threadIdx.x;
  const int w = tid >> 6, lane = tid & 63, quad = lane >> 4, l15 = lane & 15;
  const int srow = lane >> 2, scol = (lane & 3) * 8;
  const unsigned short* Arow0 = Og + (size_t)(bm * 64) * 1024;
  const unsigned short* Brow0 = WoT + (size_t)(bn * 128) * 1024;
  for (int k0 = 0; k0 < 1024; k0 += 64) {
    __syncthreads();
    #pragma unroll
    for (int i = 0; i < 2; ++i) {
      int arow = w * 16 + srow;
      async_ld16(Arow0 + (size_t)arow * 1024 + k0 + i * 32 + scol,
                 Als + i * 2048 + w * 512 + lane * 8);
    }
    #pragma unroll
    for (int i = 0; i < 4; ++i) {
      int brow = (i & 1) * 64 + w * 16 + srow;
      int kadd = (i >> 1) * 32 + scol;
      async_ld16(Brow0 + (size_t)brow * 1024 + k0 + kadd,
                 Bls + i * 2048 + w * 512 + lane * 8);
    }
    __syncthreads();
    #pragma unroll
    for (int kk2 = 0; kk2 < 2; ++kk2) {
      bf16x8 a[4], b[2];
      #pragma unroll
      for (int mi = 0; mi < 4; ++mi)
        a[mi] = *(const bf16x8*)(Als + kk2 * 2048 + (mi * 16 + l15) * 32 + quad * 8);
      #pragma unroll
      for (int ni = 0; ni < 2; ++ni)
        b[ni] = *(const bf16x8*)(Bls + kk2 * 4096 + (w * 32 + ni * 16 + l15) * 32 + quad * 8);
      #pragma unroll
      for (int mi = 0; mi < 4; ++mi)
        #pragma unroll
        for (int ni = 0; ni < 2; ++ni)
          acc[mi][ni] = __builtin_amdgcn_mfma_f32_16x16x32_bf16(a[mi], b[ni], acc[mi][ni], 0, 0, 0);
    }
  }
  #pragma unroll
  for (int mi = 0; mi < 4; ++mi)
    #pragma unroll
    for (int r = 0; r < 4; ++r) {
      int mm = bm * 64 + mi * 16 + quad * 4 + r;
      #pragma unroll
      for (int ni = 0; ni < 2; ++ni) {
        int n = bn * 128 + w * 32 + ni * 16 + l15;
        Cout[(size_t)mm * 1024 + n] = acc[mi][ni][r];  // 64B full line per quad
      }
    }
}

extern "C" void kernel_launch(void* const* d_in, const int* in_sizes, int n_in,
                              void* d_out, int out_size, void* d_ws, size_t ws_size,
                              hipStream_t stream) {
  const float* x      = (const float*)d_in[0];
  const float* w_qkv  = (const float*)d_in[1];
  const float* q_bias = (const float*)d_in[2];
  const float* v_bias = (const float*)d_in[3];
  const float* w_out  = (const float*)d_in[4];
  float* out = (float*)d_out;

  char* ws = (char*)d_ws;                       // 48.5 MB used
  unsigned short* Xb    = (unsigned short*)(ws);                  //  8 MB  x bf16 [4096][1024]
  unsigned short* WqkvT = (unsigned short*)(ws + (8u  << 20));    //  6 MB  w_qkv^T bf16 [3072][1024]
  unsigned short* WoT   = (unsigned short*)(ws + (14u << 20));    //  2 MB  w_out^T bf16 [1024][1024]
  unsigned short* Qg    = (unsigned short*)(ws + (16u << 20));    //  8 MB  Q [B,H,S,D] (x 0.125*log2e)
  unsigned short* Kg    = (unsigned short*)(ws + (24u << 20));    //  8 MB  K [B,H,S,D]
  unsigned short* Vtg   = (unsigned short*)(ws + (32u << 20));    //  8 MB  V^T [B,H,D,S]
  unsigned short* Og    = (unsigned short*)(ws + (40u << 20));    //  8 MB  attn out [B,S,C]
  float2* ropeT         = (float2*)(ws + (48u << 20));            // 512 KB [2048][32] (cos,sin)

  prep<<<5376, 256, 0, stream>>>(x, w_qkv, w_out, Xb, WqkvT, WoT, ropeT);
  qkv_gemm<<<dim3(24, 32), 256, 0, stream>>>(Xb, WqkvT, q_bias, v_bias, ropeT, Qg, Kg, Vtg);
  attn_fwd<<<1024, 256, 0, stream>>>(Qg, Kg, Vtg, Og);
  out_gemm<<<dim3(8, 64), 256, 0, stream>>>(Og, WoT, out);
}